// Round 3
// baseline (615.723 us; speedup 1.0000x reference)
//
#include <hip/hip_runtime.h>
#include <stdint.h>
#include <stddef.h>

typedef __attribute__((ext_vector_type(8))) short bf16x8;
typedef __attribute__((ext_vector_type(4))) float f32x4;
typedef __attribute__((ext_vector_type(4))) uint32_t u32x4;

#define DEVINL static __device__ __forceinline__

DEVINL float b2f(uint16_t u) {
  uint32_t x = ((uint32_t)u) << 16;
  float f;
  __builtin_memcpy(&f, &x, 4);
  return f;
}

DEVINL uint16_t f2b(float f) {
  uint32_t u;
  __builtin_memcpy(&u, &f, 4);
  return (uint16_t)((u + 0x7fffu + ((u >> 16) & 1u)) >> 16);
}

// ---------------- runtime dtype/mask detection ----------------
// hdr[0] = 1 if float tensors are fp32 (else bf16); hdr[1..8] = lengths[b]
__global__ void detect_kernel(const void* __restrict__ wq, const void* __restrict__ mask,
                              const void* __restrict__ bq, const void* __restrict__ bk,
                              const void* __restrict__ bv, const void* __restrict__ bo,
                              int* __restrict__ hdr, float* __restrict__ bias) {
  __shared__ int sflag, smask32, slen[8];
  const int tid = threadIdx.x;
  if (tid == 0) { sflag = 0; smask32 = 0; }
  if (tid < 8) slen[tid] = 0;
  __syncthreads();
  const uint16_t* w16 = (const uint16_t*)wq;
  int f = 0;
  for (int i = tid; i < 4096; i += 256) {
    uint16_t u = w16[i];
    uint32_t e = (u >> 7) & 0xFFu;
    if (fabsf(b2f(u)) > 0.25f || e == 0xFFu) f = 1;
  }
  if (f) atomicOr(&sflag, 1);
  const uint8_t* mb = (const uint8_t*)mask;
  int m32 = 0;
  for (int i = tid; i < 8191; i += 256) {
    if ((i & 1023) != 1023 && mb[i] != 0 && mb[i + 1] == 0) m32 = 1;
  }
  if (m32) atomicOr(&smask32, 1);
  __syncthreads();
  if (smask32) {
    const int* mi = (const int*)mask;
    for (int i = tid; i < 8192; i += 256) { if (mi[i] == 0) atomicAdd(&slen[i >> 10], 1); }
  } else {
    for (int i = tid; i < 8192; i += 256) { if (mb[i] == 0) atomicAdd(&slen[i >> 10], 1); }
  }
  __syncthreads();
  if (tid == 0) hdr[0] = sflag;
  if (tid < 8) hdr[1 + tid] = slen[tid];
  const void* bs[4] = {bq, bk, bv, bo};
  for (int j = 0; j < 4; ++j) {
    for (int i = tid; i < 1024; i += 256) {
      float v = sflag ? ((const float*)bs[j])[i] : b2f(((const uint16_t*)bs[j])[i]);
      bias[j * 1024 + i] = v;
    }
  }
}

// ---------------- GEMM: C[M,1024] = A[M,1024] @ W[1024,1024]^T + bias ----------------
enum { MQ = 0, MK = 1, MV = 2, MO = 3 };

DEVINL u32x4 load8(const void* __restrict__ src, bool f32, size_t eoff) {
  if (!f32) {
    return *(const u32x4*)((const uint16_t*)src + eoff);
  }
  const float* p = (const float*)src + eoff;
  const f32x4 a = *(const f32x4*)p;
  const f32x4 c = *(const f32x4*)(p + 4);
  u32x4 r;
  r[0] = (uint32_t)f2b(a[0]) | ((uint32_t)f2b(a[1]) << 16);
  r[1] = (uint32_t)f2b(a[2]) | ((uint32_t)f2b(a[3]) << 16);
  r[2] = (uint32_t)f2b(c[0]) | ((uint32_t)f2b(c[1]) << 16);
  r[3] = (uint32_t)f2b(c[2]) | ((uint32_t)f2b(c[3]) << 16);
  return r;
}

template <int MODE>
__global__ __launch_bounds__(256)
void gemm_bt(const void* __restrict__ Ar, const void* __restrict__ Wr,
             const float* __restrict__ bias, const int* __restrict__ hdr,
             void* __restrict__ outp, float scale, int aUseFlag) {
  constexpr int KD = 1024;
  __shared__ __align__(16) uint16_t lA[128][80];
  __shared__ __align__(16) uint16_t lB[128][80];
  const int tid = threadIdx.x;
  const int bm = blockIdx.x, bn = blockIdx.y;
  const int isf = hdr[0];
  const bool aF32 = (aUseFlag != 0) && (isf != 0);
  const bool wF32 = (isf != 0);
  const int lane = tid & 63, wave = tid >> 6;
  const int wm = wave >> 1, wn = wave & 1;
  const int g = lane >> 4, cc = lane & 15;
  const int srow = tid >> 3;
  const int scol = (tid & 7) * 8;

  f32x4 acc[4][4];
#pragma unroll
  for (int i = 0; i < 4; ++i)
#pragma unroll
    for (int j = 0; j < 4; ++j) acc[i][j] = (f32x4){0.f, 0.f, 0.f, 0.f};

  u32x4 ra[4], rb[4];
#pragma unroll
  for (int c = 0; c < 4; ++c) {
    ra[c] = load8(Ar, aF32, (size_t)(bm * 128 + srow + c * 32) * KD + scol);
    rb[c] = load8(Wr, wF32, (size_t)(bn * 128 + srow + c * 32) * KD + scol);
  }
  for (int kt = 0; kt < KD / 64; ++kt) {
    __syncthreads();
#pragma unroll
    for (int c = 0; c < 4; ++c) {
      *(u32x4*)&lA[srow + c * 32][scol] = ra[c];
      *(u32x4*)&lB[srow + c * 32][scol] = rb[c];
    }
    __syncthreads();
    if (kt + 1 < KD / 64) {
#pragma unroll
      for (int c = 0; c < 4; ++c) {
        ra[c] = load8(Ar, aF32, (size_t)(bm * 128 + srow + c * 32) * KD + (kt + 1) * 64 + scol);
        rb[c] = load8(Wr, wF32, (size_t)(bn * 128 + srow + c * 32) * KD + (kt + 1) * 64 + scol);
      }
    }
#pragma unroll
    for (int kk = 0; kk < 2; ++kk) {
      bf16x8 af[4], bfr[4];
#pragma unroll
      for (int mi = 0; mi < 4; ++mi) af[mi] = *(const bf16x8*)&lA[wm * 64 + mi * 16 + cc][kk * 32 + g * 8];
#pragma unroll
      for (int ni = 0; ni < 4; ++ni) bfr[ni] = *(const bf16x8*)&lB[wn * 64 + ni * 16 + cc][kk * 32 + g * 8];
#pragma unroll
      for (int mi = 0; mi < 4; ++mi)
#pragma unroll
        for (int ni = 0; ni < 4; ++ni)
          acc[mi][ni] = __builtin_amdgcn_mfma_f32_16x16x32_bf16(af[mi], bfr[ni], acc[mi][ni], 0, 0, 0);
    }
  }
#pragma unroll
  for (int mi = 0; mi < 4; ++mi) {
#pragma unroll
    for (int ni = 0; ni < 4; ++ni) {
      const int col = bn * 128 + wn * 64 + ni * 16 + cc;
      const float bv = bias[col];
      const int r0 = bm * 128 + wm * 64 + mi * 16 + g * 4;
#pragma unroll
      for (int r = 0; r < 4; ++r) {
        const int row = r0 + r;
        const float v = (acc[mi][ni][r] + bv) * scale;
        if (MODE == MQ) {
          const int b = row >> 10, t = row & 1023, h = col >> 6, d = col & 63;
          ((uint16_t*)outp)[(((size_t)(b * 16 + h) << 10) + t) * 64 + d] = f2b(v);
        } else if (MODE == MK) {
          const int s = row >> 3, b = row & 7, h = col >> 6, d = col & 63;
          ((uint16_t*)outp)[(((size_t)(b * 16 + h) << 10) + s) * 64 + d] = f2b(v);
        } else if (MODE == MV) {
          const int s = row >> 3, b = row & 7, h = col >> 6, d = col & 63;
          ((uint16_t*)outp)[(((size_t)(b * 16 + h) << 6) + d) * 1024 + s] = f2b(v);
        } else {
          const size_t o = (size_t)row * 1024 + col;
          if (isf) ((float*)outp)[o] = v;
          else ((uint16_t*)outp)[o] = f2b(v);
        }
      }
    }
  }
}

// ---------------- fused attention (v2: 1024 threads, 16 waves) ----------------
// block = (b, t-tile of 16). wave w: wq = w&3 (S-quarter), wh = w>>2 (head slot).
// 4 head-group iterations; head h = hg*4 + wh. Per-wave LDS region (16x272 bf16)
// is reused as: exp-score stage -> pv f32 buffer (overlay) -> wmean bf16 partial.
__global__ __launch_bounds__(1024, 4)
void attn_kernel(const uint16_t* __restrict__ Qh, const uint16_t* __restrict__ Kh,
                 const uint16_t* __restrict__ Vh, const int* __restrict__ hdr,
                 uint16_t* __restrict__ AP, uint16_t* __restrict__ Wm) {
  __shared__ __align__(16) uint16_t wsg[16][16][272];  // 139264 B
  __shared__ float sumbuf[4][16][4];                   // [wh][t][wq]
  const int tid = threadIdx.x, lane = tid & 63, w = tid >> 6;
  const int wq = w & 3, wh = w >> 2;
  const int b = blockIdx.x & 7, tt = blockIdx.x >> 3;  // b low bits -> per-XCD K/V locality
  const int len = hdr[1 + b];
  const int g = lane >> 4, cc = lane & 15;

  float wmean[16][4];
#pragma unroll
  for (int j = 0; j < 16; ++j)
#pragma unroll
    for (int r = 0; r < 4; ++r) wmean[j][r] = 0.f;

  for (int hg = 0; hg < 4; ++hg) {
    const int h = hg * 4 + wh;
    const uint16_t* Qb = Qh + ((size_t)(b * 16 + h) << 16);
    const uint16_t* Kb = Kh + ((size_t)(b * 16 + h) << 16);
    const uint16_t* Vb = Vh + ((size_t)(b * 16 + h) << 16);

    const bf16x8 qf0 = *(const bf16x8*)(Qb + (((size_t)(tt * 16 + cc)) << 6) + g * 8);
    const bf16x8 qf1 = *(const bf16x8*)(Qb + (((size_t)(tt * 16 + cc)) << 6) + 32 + g * 8);

    // QK^T + mask + exp; stage exp'd scores to LDS immediately (no sc[] array)
    float psum[4] = {0.f, 0.f, 0.f, 0.f};
#pragma unroll
    for (int j = 0; j < 16; ++j) {
      const uint16_t* kp = Kb + (((size_t)(wq * 256 + j * 16 + cc)) << 6) + g * 8;
      const bf16x8 k0 = *(const bf16x8*)kp;
      const bf16x8 k1 = *(const bf16x8*)(kp + 32);
      f32x4 a = {0.f, 0.f, 0.f, 0.f};
      a = __builtin_amdgcn_mfma_f32_16x16x32_bf16(qf0, k0, a, 0, 0, 0);
      a = __builtin_amdgcn_mfma_f32_16x16x32_bf16(qf1, k1, a, 0, 0, 0);
      const int s = wq * 256 + j * 16 + cc;
      const bool msk = (s >= len);
#pragma unroll
      for (int r = 0; r < 4; ++r) {
        const float v = msk ? 0.f : __expf(a[r]);
        psum[r] += v;
        wsg[w][g * 4 + r][j * 16 + cc] = f2b(v);
      }
    }
#pragma unroll
    for (int off = 8; off >= 1; off >>= 1)
#pragma unroll
      for (int r = 0; r < 4; ++r) psum[r] += __shfl_xor(psum[r], off, 64);
    if (cc == 0) {
#pragma unroll
      for (int r = 0; r < 4; ++r) sumbuf[wh][g * 4 + r][wq] = psum[r];
    }
    __syncthreads();  // B1: sumbuf ready (cross-wq within wh-group)

    float winv[4];
#pragma unroll
    for (int r = 0; r < 4; ++r) {
      const int tl = g * 4 + r;
      winv[r] = 1.f / (sumbuf[wh][tl][0] + sumbuf[wh][tl][1] + sumbuf[wh][tl][2] + sumbuf[wh][tl][3]);
    }
    // wmean accumulate from staged scores (readback, own region only)
#pragma unroll
    for (int j = 0; j < 16; ++j)
#pragma unroll
      for (int r = 0; r < 4; ++r)
        wmean[j][r] += b2f(wsg[w][g * 4 + r][j * 16 + cc]) * winv[r];

    // PV: A = staged P~ (t x s), B = V via V^T rows (contiguous in s)
    f32x4 pv[4];
#pragma unroll
    for (int nf = 0; nf < 4; ++nf) pv[nf] = (f32x4){0.f, 0.f, 0.f, 0.f};
#pragma unroll
    for (int kc = 0; kc < 8; ++kc) {
      const bf16x8 af = *(const bf16x8*)&wsg[w][cc][kc * 32 + g * 8];
#pragma unroll
      for (int nf = 0; nf < 4; ++nf) {
        const bf16x8 vf = *(const bf16x8*)(Vb + (((size_t)(nf * 16 + cc)) << 10) + wq * 256 + kc * 32 + g * 8);
        pv[nf] = __builtin_amdgcn_mfma_f32_16x16x32_bf16(af, vf, pv[nf], 0, 0, 0);
      }
    }
    // pv -> own region overlay (f32 [16][64], 4KB <= 8704B region)
    {
      float* pvb = (float*)&wsg[w][0][0];
#pragma unroll
      for (int nf = 0; nf < 4; ++nf)
#pragma unroll
        for (int r = 0; r < 4; ++r)
          pvb[(g * 4 + r) * 64 + nf * 16 + cc] = pv[nf][r];
    }
    __syncthreads();  // B2: all pv buffers ready

    // AP write: each wh-group (256 threads) reduces its head across wq quarters
    {
      const int whg = tid >> 8;
      const int tl = (tid & 255) >> 4;
      const int d0 = (tid & 15) * 4;
      const int hh = hg * 4 + whg;
      const float inv = 1.f / (sumbuf[whg][tl][0] + sumbuf[whg][tl][1] + sumbuf[whg][tl][2] + sumbuf[whg][tl][3]);
      f32x4 s0 = *(const f32x4*)&((const float*)&wsg[whg * 4 + 0][0][0])[tl * 64 + d0];
      f32x4 s1 = *(const f32x4*)&((const float*)&wsg[whg * 4 + 1][0][0])[tl * 64 + d0];
      f32x4 s2 = *(const f32x4*)&((const float*)&wsg[whg * 4 + 2][0][0])[tl * 64 + d0];
      f32x4 s3 = *(const f32x4*)&((const float*)&wsg[whg * 4 + 3][0][0])[tl * 64 + d0];
      uint16_t o4[4];
#pragma unroll
      for (int i = 0; i < 4; ++i) o4[i] = f2b((s0[i] + s1[i] + s2[i] + s3[i]) * inv);
      uint64_t pk;
      __builtin_memcpy(&pk, o4, 8);
      *(uint64_t*)(AP + ((((size_t)(tt * 16 + tl)) * 8 + b) << 10) + hh * 64 + d0) = pk;
    }
    __syncthreads();  // B3: safe to reuse regions next head-group
  }

  // final: stage wmean partials (bf16) per wave, then cross-head-group sum -> Wm[b][t][s]
#pragma unroll
  for (int j = 0; j < 16; ++j)
#pragma unroll
    for (int r = 0; r < 4; ++r)
      wsg[w][g * 4 + r][j * 16 + cc] = f2b(wmean[j][r]);
  __syncthreads();  // B4: partials ready

  {
    // wave w handles output t-row = w; lanes cover 16 s-cols each
    const int sq = lane >> 4;           // source quarter
    const int sl = (lane & 15) * 16;    // s offset within quarter
    float accv[16];
#pragma unroll
    for (int i = 0; i < 16; ++i) accv[i] = 0.f;
#pragma unroll
    for (int p = 0; p < 4; ++p) {
      const uint16_t* src = &wsg[sq + 4 * p][w][sl];
      const bf16x8 v0 = *(const bf16x8*)src;
      const bf16x8 v1 = *(const bf16x8*)(src + 8);
#pragma unroll
      for (int i = 0; i < 8; ++i) {
        accv[i] += b2f((uint16_t)v0[i]);
        accv[8 + i] += b2f((uint16_t)v1[i]);
      }
    }
    bf16x8 ov0, ov1;
#pragma unroll
    for (int i = 0; i < 8; ++i) {
      ov0[i] = (short)f2b(accv[i] * 0.0625f);
      ov1[i] = (short)f2b(accv[8 + i] * 0.0625f);
    }
    uint16_t* dst = Wm + ((size_t)(b * 1024 + tt * 16 + w) << 10) + sq * 256 + sl;
    *(bf16x8*)dst = ov0;
    *(bf16x8*)(dst + 8) = ov1;
  }
}

// ---------------- weights transpose: Wm[b][t][s] bf16 -> out (S,T,B) ----------------
__global__ __launch_bounds__(256)
void wtrans_kernel(const uint16_t* __restrict__ Wm, const int* __restrict__ hdr,
                   void* __restrict__ outBase) {
  __shared__ uint16_t lt[8][32][68];
  const int tid = threadIdx.x;
  const int s0 = blockIdx.x * 64, t0 = blockIdx.y * 32;
  const int isf = hdr[0];
  const int rr = tid >> 4;
  const int sc = (tid & 15) * 4;
#pragma unroll
  for (int p = 0; p < 16; ++p) {
    const int row = p * 16 + rr;  // 0..255 : b = row>>5, t = row&31
    const int b = row >> 5, t = row & 31;
    const uint64_t v = *(const uint64_t*)(Wm + (((size_t)(b * 1024 + t0 + t)) << 10) + s0 + sc);
    *(uint64_t*)&lt[b][t][sc] = v;
  }
  __syncthreads();
#pragma unroll
  for (int p = 0; p < 8; ++p) {
    const int pair = p * 256 + tid;
    const int t = pair & 31, s = pair >> 5;
    const size_t o = 8388608 + ((size_t)(s0 + s) * 1024 + (t0 + t)) * 8;
    if (isf) {
      f32x4 v0, v1;
#pragma unroll
      for (int b = 0; b < 4; ++b) v0[b] = b2f(lt[b][t][s]);
#pragma unroll
      for (int b = 0; b < 4; ++b) v1[b] = b2f(lt[b + 4][t][s]);
      *(f32x4*)((float*)outBase + o) = v0;
      *(f32x4*)((float*)outBase + o + 4) = v1;
    } else {
      u32x4 v;
#pragma unroll
      for (int q = 0; q < 4; ++q)
        v[q] = (uint32_t)lt[2 * q][t][s] | ((uint32_t)lt[2 * q + 1][t][s] << 16);
      *(u32x4*)((uint16_t*)outBase + o) = v;
    }
  }
}

__global__ void fill_pattern(uint32_t* p, size_t n) {
  size_t i = (size_t)blockIdx.x * 256 + threadIdx.x;
  const size_t stride = (size_t)gridDim.x * 256;
  for (; i < n; i += stride) p[i] = 0x3f3f3f3fu;
}

extern "C" void kernel_launch(void* const* d_in, const int* in_sizes, int n_in,
                              void* d_out, int out_size, void* d_ws, size_t ws_size,
                              hipStream_t stream) {
  char* ws = (char*)d_ws;
  int* hdr = (int*)ws;
  float* bias = (float*)(ws + 4096);
  uint16_t* Q = (uint16_t*)(ws + (1u << 20));
  uint16_t* K = Q + 8388608;   // 8*16*1024*64
  uint16_t* V = K + 8388608;
  uint16_t* AP = V + 8388608;
  uint16_t* Wm = AP + 8388608;
  const size_t need = (1ull << 20) + 5ull * 16777216ull;  // header + 5 x 16MB
  if (ws_size < need) {  // diagnostic fallback: distinctive pattern
    fill_pattern<<<1024, 256, 0, stream>>>((uint32_t*)d_out, (size_t)out_size / 2);
    return;
  }

  detect_kernel<<<1, 256, 0, stream>>>(d_in[3], d_in[2], d_in[4], d_in[6], d_in[8], d_in[10], hdr, bias);

  dim3 gg(64, 8);
  gemm_bt<MQ><<<gg, 256, 0, stream>>>(d_in[0], d_in[3], bias, hdr, Q, 0.125f, 1);
  gemm_bt<MK><<<gg, 256, 0, stream>>>(d_in[1], d_in[5], bias + 1024, hdr, K, 1.f, 1);
  gemm_bt<MV><<<gg, 256, 0, stream>>>(d_in[1], d_in[7], bias + 2048, hdr, V, 1.f, 1);

  attn_kernel<<<512, 1024, 0, stream>>>(Q, K, V, hdr, AP, Wm);

  wtrans_kernel<<<dim3(16, 32), 256, 0, stream>>>(Wm, hdr, d_out);

  gemm_bt<MO><<<gg, 256, 0, stream>>>(AP, d_in[9], bias + 3072, hdr, d_out, 1.f, 0);
}

// Round 4
// 425.643 us; speedup vs baseline: 1.4466x; 1.4466x over previous
//
#include <hip/hip_runtime.h>
#include <stdint.h>
#include <stddef.h>

typedef __attribute__((ext_vector_type(8))) short bf16x8;
typedef __attribute__((ext_vector_type(4))) float f32x4;
typedef __attribute__((ext_vector_type(4))) uint32_t u32x4;

#define DEVINL static __device__ __forceinline__

DEVINL float b2f(uint16_t u) {
  uint32_t x = ((uint32_t)u) << 16;
  float f;
  __builtin_memcpy(&f, &x, 4);
  return f;
}

DEVINL uint16_t f2b(float f) {
  uint32_t u;
  __builtin_memcpy(&u, &f, 4);
  return (uint16_t)((u + 0x7fffu + ((u >> 16) & 1u)) >> 16);
}

// ---------------- runtime dtype/mask detection ----------------
// hdr[0] = 1 if float tensors are fp32 (else bf16); hdr[1..8] = lengths[b]
__global__ void detect_kernel(const void* __restrict__ wq, const void* __restrict__ mask,
                              const void* __restrict__ bq, const void* __restrict__ bk,
                              const void* __restrict__ bv, const void* __restrict__ bo,
                              int* __restrict__ hdr, float* __restrict__ bias) {
  __shared__ int sflag, smask32, slen[8];
  const int tid = threadIdx.x;
  if (tid == 0) { sflag = 0; smask32 = 0; }
  if (tid < 8) slen[tid] = 0;
  __syncthreads();
  const uint16_t* w16 = (const uint16_t*)wq;
  int f = 0;
  for (int i = tid; i < 4096; i += 256) {
    uint16_t u = w16[i];
    uint32_t e = (u >> 7) & 0xFFu;
    if (fabsf(b2f(u)) > 0.25f || e == 0xFFu) f = 1;
  }
  if (f) atomicOr(&sflag, 1);
  const uint8_t* mb = (const uint8_t*)mask;
  int m32 = 0;
  for (int i = tid; i < 8191; i += 256) {
    if ((i & 1023) != 1023 && mb[i] != 0 && mb[i + 1] == 0) m32 = 1;
  }
  if (m32) atomicOr(&smask32, 1);
  __syncthreads();
  if (smask32) {
    const int* mi = (const int*)mask;
    for (int i = tid; i < 8192; i += 256) { if (mi[i] == 0) atomicAdd(&slen[i >> 10], 1); }
  } else {
    for (int i = tid; i < 8192; i += 256) { if (mb[i] == 0) atomicAdd(&slen[i >> 10], 1); }
  }
  __syncthreads();
  if (tid == 0) hdr[0] = sflag;
  if (tid < 8) hdr[1 + tid] = slen[tid];
  const void* bs[4] = {bq, bk, bv, bo};
  for (int j = 0; j < 4; ++j) {
    for (int i = tid; i < 1024; i += 256) {
      float v = sflag ? ((const float*)bs[j])[i] : b2f(((const uint16_t*)bs[j])[i]);
      bias[j * 1024 + i] = v;
    }
  }
}

// ---------------- fp32 -> bf16 conversion pass (or bf16 copy) ----------------
// seg0: s0 -> d0 (8388608 elems), seg1: s1 -> d1 (8388608), segs 2-5: W -> d2+k*1048576
__global__ __launch_bounds__(256)
void convert_kernel(const void* __restrict__ s0, const void* __restrict__ s1,
                    const void* __restrict__ s2, const void* __restrict__ s3,
                    const void* __restrict__ s4, const void* __restrict__ s5,
                    uint16_t* __restrict__ d0, uint16_t* __restrict__ d1,
                    uint16_t* __restrict__ d2, const int* __restrict__ hdr, int doW) {
  const int isf = hdr[0];
  const size_t n01 = 1048576;  // 8-elem groups per big segment
  const size_t nw = 131072;    // 8-elem groups per weight
  const size_t total = doW ? (2 * n01 + 4 * nw) : (2 * n01);
  size_t gid = (size_t)blockIdx.x * 256 + threadIdx.x;
  const size_t stride = (size_t)gridDim.x * 256;
  for (; gid < total; gid += stride) {
    const void* sp;
    uint16_t* dp;
    size_t off;
    if (gid < n01) { sp = s0; dp = d0; off = gid; }
    else if (gid < 2 * n01) { sp = s1; dp = d1; off = gid - n01; }
    else {
      const size_t w = (gid - 2 * n01) >> 17;
      off = (gid - 2 * n01) & (nw - 1);
      sp = (w == 0) ? s2 : (w == 1) ? s3 : (w == 2) ? s4 : s5;
      dp = d2 + w * 1048576;
    }
    if (isf) {
      const float* fp = (const float*)sp + off * 8;
      const f32x4 a = *(const f32x4*)fp;
      const f32x4 c = *(const f32x4*)(fp + 4);
      u32x4 r;
      r[0] = (uint32_t)f2b(a[0]) | ((uint32_t)f2b(a[1]) << 16);
      r[1] = (uint32_t)f2b(a[2]) | ((uint32_t)f2b(a[3]) << 16);
      r[2] = (uint32_t)f2b(c[0]) | ((uint32_t)f2b(c[1]) << 16);
      r[3] = (uint32_t)f2b(c[2]) | ((uint32_t)f2b(c[3]) << 16);
      *(u32x4*)(dp + off * 8) = r;
    } else {
      *(u32x4*)(dp + off * 8) = *(const u32x4*)((const uint16_t*)sp + off * 8);
    }
  }
}

// ---------------- GEMM: C[M,1024] = A[M,1024] @ W[1024,1024]^T + bias ----------------
// A is bf16 (ws). W is bf16 (converted) or fp32 per wIsBf16/hdr.
enum { MQ = 0, MK = 1, MV = 2, MO = 3 };

DEVINL u32x4 load8w(const void* __restrict__ src, bool f32, size_t eoff) {
  if (!f32) {
    return *(const u32x4*)((const uint16_t*)src + eoff);
  }
  const float* p = (const float*)src + eoff;
  const f32x4 a = *(const f32x4*)p;
  const f32x4 c = *(const f32x4*)(p + 4);
  u32x4 r;
  r[0] = (uint32_t)f2b(a[0]) | ((uint32_t)f2b(a[1]) << 16);
  r[1] = (uint32_t)f2b(a[2]) | ((uint32_t)f2b(a[3]) << 16);
  r[2] = (uint32_t)f2b(c[0]) | ((uint32_t)f2b(c[1]) << 16);
  r[3] = (uint32_t)f2b(c[2]) | ((uint32_t)f2b(c[3]) << 16);
  return r;
}

template <int MODE>
__global__ __launch_bounds__(256)
void gemm_bt(const uint16_t* __restrict__ Ab, const void* __restrict__ Wr,
             const float* __restrict__ bias, const int* __restrict__ hdr,
             void* __restrict__ outp, float scale, int wIsBf16) {
  constexpr int KD = 1024;
  __shared__ __align__(16) uint16_t lA[128][80];
  __shared__ __align__(16) uint16_t lB[128][80];
  const int tid = threadIdx.x;
  const int bm = blockIdx.x, bn = blockIdx.y;
  const int isf = hdr[0];
  const bool wF32 = (wIsBf16 == 0) && (isf != 0);
  const int lane = tid & 63, wave = tid >> 6;
  const int wm = wave >> 1, wn = wave & 1;
  const int g = lane >> 4, cc = lane & 15;
  const int srow = tid >> 3;
  const int scol = (tid & 7) * 8;

  f32x4 acc[4][4];
#pragma unroll
  for (int i = 0; i < 4; ++i)
#pragma unroll
    for (int j = 0; j < 4; ++j) acc[i][j] = (f32x4){0.f, 0.f, 0.f, 0.f};

  u32x4 ra[4], rb[4];
#pragma unroll
  for (int c = 0; c < 4; ++c) {
    ra[c] = *(const u32x4*)(Ab + (size_t)(bm * 128 + srow + c * 32) * KD + scol);
    rb[c] = load8w(Wr, wF32, (size_t)(bn * 128 + srow + c * 32) * KD + scol);
  }
  for (int kt = 0; kt < KD / 64; ++kt) {
    __syncthreads();
#pragma unroll
    for (int c = 0; c < 4; ++c) {
      *(u32x4*)&lA[srow + c * 32][scol] = ra[c];
      *(u32x4*)&lB[srow + c * 32][scol] = rb[c];
    }
    __syncthreads();
    if (kt + 1 < KD / 64) {
#pragma unroll
      for (int c = 0; c < 4; ++c) {
        ra[c] = *(const u32x4*)(Ab + (size_t)(bm * 128 + srow + c * 32) * KD + (kt + 1) * 64 + scol);
        rb[c] = load8w(Wr, wF32, (size_t)(bn * 128 + srow + c * 32) * KD + (kt + 1) * 64 + scol);
      }
    }
#pragma unroll
    for (int kk = 0; kk < 2; ++kk) {
      bf16x8 af[4], bfr[4];
#pragma unroll
      for (int mi = 0; mi < 4; ++mi) af[mi] = *(const bf16x8*)&lA[wm * 64 + mi * 16 + cc][kk * 32 + g * 8];
#pragma unroll
      for (int ni = 0; ni < 4; ++ni) bfr[ni] = *(const bf16x8*)&lB[wn * 64 + ni * 16 + cc][kk * 32 + g * 8];
#pragma unroll
      for (int mi = 0; mi < 4; ++mi)
#pragma unroll
        for (int ni = 0; ni < 4; ++ni)
          acc[mi][ni] = __builtin_amdgcn_mfma_f32_16x16x32_bf16(af[mi], bfr[ni], acc[mi][ni], 0, 0, 0);
    }
  }
#pragma unroll
  for (int mi = 0; mi < 4; ++mi) {
#pragma unroll
    for (int ni = 0; ni < 4; ++ni) {
      const int col = bn * 128 + wn * 64 + ni * 16 + cc;
      const float bv = bias[col];
      const int r0 = bm * 128 + wm * 64 + mi * 16 + g * 4;
#pragma unroll
      for (int r = 0; r < 4; ++r) {
        const int row = r0 + r;
        const float v = (acc[mi][ni][r] + bv) * scale;
        if (MODE == MQ) {
          const int b = row >> 10, t = row & 1023, h = col >> 6, d = col & 63;
          ((uint16_t*)outp)[(((size_t)(b * 16 + h) << 10) + t) * 64 + d] = f2b(v);
        } else if (MODE == MK) {
          const int s = row >> 3, b = row & 7, h = col >> 6, d = col & 63;
          ((uint16_t*)outp)[(((size_t)(b * 16 + h) << 10) + s) * 64 + d] = f2b(v);
        } else if (MODE == MV) {
          const int s = row >> 3, b = row & 7, h = col >> 6, d = col & 63;
          ((uint16_t*)outp)[(((size_t)(b * 16 + h) << 6) + d) * 1024 + s] = f2b(v);
        } else {
          const size_t o = (size_t)row * 1024 + col;
          if (isf) ((float*)outp)[o] = v;
          else ((uint16_t*)outp)[o] = f2b(v);
        }
      }
    }
  }
}

// ---------------- fused attention (v3: 256 thr, deep prefetch pipelines) ----------------
// block = (b, t-tile of 16). 4 waves split S (256 each). Loop h=0..15.
// K-loads 4-deep prefetch; V-loads 4-deep; sc in regs; 3 barriers/head.
__global__ __launch_bounds__(256)
void attn_kernel(const uint16_t* __restrict__ Qh, const uint16_t* __restrict__ Kh,
                 const uint16_t* __restrict__ Vh, const int* __restrict__ hdr,
                 uint16_t* __restrict__ AP, uint16_t* __restrict__ Wm) {
  __shared__ __align__(16) uint16_t wstage[4][16][272];  // 34816 B
  __shared__ float pvbuf[4][16][68];                     // 17408 B (padded: kills stride-256 conflicts)
  __shared__ float sumbuf[16][4];
  const int tid = threadIdx.x, lane = tid & 63, wave = tid >> 6;
  const int b = blockIdx.x & 7, tt = blockIdx.x >> 3;  // b low bits -> per-XCD K/V locality
  const int len = hdr[1 + b];
  const int g = lane >> 4, cc = lane & 15;

  float wmean[16][4];
#pragma unroll
  for (int j = 0; j < 16; ++j)
#pragma unroll
    for (int r = 0; r < 4; ++r) wmean[j][r] = 0.f;

  for (int h = 0; h < 16; ++h) {
    const uint16_t* Qb = Qh + ((size_t)(b * 16 + h) << 16);
    const uint16_t* Kb = Kh + ((size_t)(b * 16 + h) << 16);
    const uint16_t* Vb = Vh + ((size_t)(b * 16 + h) << 16);

    const bf16x8 qf0 = *(const bf16x8*)(Qb + (((size_t)(tt * 16 + cc)) << 6) + g * 8);
    const bf16x8 qf1 = *(const bf16x8*)(Qb + (((size_t)(tt * 16 + cc)) << 6) + 32 + g * 8);

    // ---- QK^T with 4-deep K prefetch ----
    bf16x8 pk0[4], pk1[4];
#pragma unroll
    for (int j = 0; j < 4; ++j) {
      const uint16_t* kp = Kb + (((size_t)(wave * 256 + j * 16 + cc)) << 6) + g * 8;
      pk0[j] = *(const bf16x8*)kp;
      pk1[j] = *(const bf16x8*)(kp + 32);
    }
    f32x4 sc[16];
    float psum[4] = {0.f, 0.f, 0.f, 0.f};
#pragma unroll
    for (int j = 0; j < 16; ++j) {
      const bf16x8 k0 = pk0[j & 3];
      const bf16x8 k1 = pk1[j & 3];
      if (j < 12) {
        const uint16_t* kp = Kb + (((size_t)(wave * 256 + (j + 4) * 16 + cc)) << 6) + g * 8;
        pk0[j & 3] = *(const bf16x8*)kp;
        pk1[j & 3] = *(const bf16x8*)(kp + 32);
      }
      f32x4 a = {0.f, 0.f, 0.f, 0.f};
      a = __builtin_amdgcn_mfma_f32_16x16x32_bf16(qf0, k0, a, 0, 0, 0);
      a = __builtin_amdgcn_mfma_f32_16x16x32_bf16(qf1, k1, a, 0, 0, 0);
      const int s = wave * 256 + j * 16 + cc;
      const bool msk = (s >= len);
#pragma unroll
      for (int r = 0; r < 4; ++r) {
        const float v = msk ? 0.f : __expf(a[r]);
        sc[j][r] = v;
        psum[r] += v;
      }
    }
#pragma unroll
    for (int off = 8; off >= 1; off >>= 1)
#pragma unroll
      for (int r = 0; r < 4; ++r) psum[r] += __shfl_xor(psum[r], off, 64);
    if (cc == 0) {
#pragma unroll
      for (int r = 0; r < 4; ++r) sumbuf[g * 4 + r][wave] = psum[r];
    }
    // stage P~ (bf16) to own LDS region before the barrier (overlaps)
#pragma unroll
    for (int j = 0; j < 16; ++j)
#pragma unroll
      for (int r = 0; r < 4; ++r) wstage[wave][g * 4 + r][j * 16 + cc] = f2b(sc[j][r]);
    __syncthreads();  // B1: sumbuf (and own wstage) ready

    float winv[4];
#pragma unroll
    for (int r = 0; r < 4; ++r) {
      const int tl = g * 4 + r;
      winv[r] = 1.f / (sumbuf[tl][0] + sumbuf[tl][1] + sumbuf[tl][2] + sumbuf[tl][3]);
    }
#pragma unroll
    for (int j = 0; j < 16; ++j)
#pragma unroll
      for (int r = 0; r < 4; ++r) wmean[j][r] += sc[j][r] * winv[r];

    // ---- PV with 4-deep V prefetch ----
    bf16x8 pva[4][4];
#pragma unroll
    for (int kc = 0; kc < 4; ++kc)
#pragma unroll
      for (int nf = 0; nf < 4; ++nf)
        pva[kc][nf] = *(const bf16x8*)(Vb + (((size_t)(nf * 16 + cc)) << 10) + wave * 256 + kc * 32 + g * 8);
    f32x4 pv[4];
#pragma unroll
    for (int nf = 0; nf < 4; ++nf) pv[nf] = (f32x4){0.f, 0.f, 0.f, 0.f};
#pragma unroll
    for (int kc = 0; kc < 8; ++kc) {
      bf16x8 cur[4];
#pragma unroll
      for (int nf = 0; nf < 4; ++nf) cur[nf] = pva[kc & 3][nf];
      if (kc < 4) {
#pragma unroll
        for (int nf = 0; nf < 4; ++nf)
          pva[kc & 3][nf] = *(const bf16x8*)(Vb + (((size_t)(nf * 16 + cc)) << 10) + wave * 256 + (kc + 4) * 32 + g * 8);
      }
      const bf16x8 af = *(const bf16x8*)&wstage[wave][cc][kc * 32 + g * 8];
#pragma unroll
      for (int nf = 0; nf < 4; ++nf)
        pv[nf] = __builtin_amdgcn_mfma_f32_16x16x32_bf16(af, cur[nf], pv[nf], 0, 0, 0);
    }
#pragma unroll
    for (int nf = 0; nf < 4; ++nf)
#pragma unroll
      for (int r = 0; r < 4; ++r)
        pvbuf[wave][g * 4 + r][nf * 16 + cc] = pv[nf][r];
    __syncthreads();  // B2: pv buffers ready

    {  // cross-wave reduce, normalize, store attn_pre (T,B,E) bf16
      const int tl = tid >> 4;
      const int d0 = (tid & 15) * 4;
      const float inv = 1.f / (sumbuf[tl][0] + sumbuf[tl][1] + sumbuf[tl][2] + sumbuf[tl][3]);
      const f32x4 s0 = *(const f32x4*)&pvbuf[0][tl][d0];
      const f32x4 s1 = *(const f32x4*)&pvbuf[1][tl][d0];
      const f32x4 s2 = *(const f32x4*)&pvbuf[2][tl][d0];
      const f32x4 s3 = *(const f32x4*)&pvbuf[3][tl][d0];
      uint16_t o4[4];
#pragma unroll
      for (int q = 0; q < 4; ++q) o4[q] = f2b((s0[q] + s1[q] + s2[q] + s3[q]) * inv);
      uint64_t pk;
      __builtin_memcpy(&pk, o4, 8);
      *(uint64_t*)(AP + ((((size_t)(tt * 16 + tl)) * 8 + b) << 10) + h * 64 + d0) = pk;
    }
    __syncthreads();  // B3: safe to reuse sumbuf/pvbuf/wstage next head
  }

  // final: wmean -> Wm[b][t][s] bf16 via own-region LDS staging (coalesced u64 stores)
#pragma unroll
  for (int j = 0; j < 16; ++j)
#pragma unroll
    for (int r = 0; r < 4; ++r)
      wstage[wave][g * 4 + r][j * 16 + cc] = f2b(wmean[j][r] * 0.0625f);
  __syncthreads();
#pragma unroll
  for (int t = 0; t < 16; ++t) {
    const uint64_t pk = *(const uint64_t*)&wstage[wave][t][lane * 4];
    *(uint64_t*)(Wm + (((size_t)(b * 1024 + tt * 16 + t)) << 10) + wave * 256 + lane * 4) = pk;
  }
}

// ---------------- weights transpose: Wm[b][t][s] bf16 -> out (S,T,B) ----------------
__global__ __launch_bounds__(256)
void wtrans_kernel(const uint16_t* __restrict__ Wm, const int* __restrict__ hdr,
                   void* __restrict__ outBase) {
  __shared__ uint16_t lt[8][32][68];
  const int tid = threadIdx.x;
  const int s0 = blockIdx.x * 64, t0 = blockIdx.y * 32;
  const int isf = hdr[0];
  const int rr = tid >> 4;
  const int sc = (tid & 15) * 4;
#pragma unroll
  for (int p = 0; p < 16; ++p) {
    const int row = p * 16 + rr;  // 0..255 : b = row>>5, t = row&31
    const int b = row >> 5, t = row & 31;
    const uint64_t v = *(const uint64_t*)(Wm + (((size_t)(b * 1024 + t0 + t)) << 10) + s0 + sc);
    *(uint64_t*)&lt[b][t][sc] = v;
  }
  __syncthreads();
#pragma unroll
  for (int p = 0; p < 8; ++p) {
    const int pair = p * 256 + tid;
    const int t = pair & 31, s = pair >> 5;
    const size_t o = 8388608 + ((size_t)(s0 + s) * 1024 + (t0 + t)) * 8;
    if (isf) {
      f32x4 v0, v1;
#pragma unroll
      for (int b = 0; b < 4; ++b) v0[b] = b2f(lt[b][t][s]);
#pragma unroll
      for (int b = 0; b < 4; ++b) v1[b] = b2f(lt[b + 4][t][s]);
      *(f32x4*)((float*)outBase + o) = v0;
      *(f32x4*)((float*)outBase + o + 4) = v1;
    } else {
      u32x4 v;
#pragma unroll
      for (int q = 0; q < 4; ++q)
        v[q] = (uint32_t)lt[2 * q][t][s] | ((uint32_t)lt[2 * q + 1][t][s] << 16);
      *(u32x4*)((uint16_t*)outBase + o) = v;
    }
  }
}

__global__ void fill_pattern(uint32_t* p, size_t n) {
  size_t i = (size_t)blockIdx.x * 256 + threadIdx.x;
  const size_t stride = (size_t)gridDim.x * 256;
  for (; i < n; i += stride) p[i] = 0x3f3f3f3fu;
}

extern "C" void kernel_launch(void* const* d_in, const int* in_sizes, int n_in,
                              void* d_out, int out_size, void* d_ws, size_t ws_size,
                              hipStream_t stream) {
  char* ws = (char*)d_ws;
  int* hdr = (int*)ws;
  float* bias = (float*)(ws + 4096);
  uint16_t* Q = (uint16_t*)(ws + (1u << 20));
  uint16_t* K = Q + 8388608;   // 8*16*1024*64
  uint16_t* V = K + 8388608;
  uint16_t* AP = V + 8388608;  // also dec_b before attn runs
  uint16_t* Wm = AP + 8388608; // also src_b before attn runs
  uint16_t* dec_b = AP;        // overlay: consumed by Q-GEMM before attn writes AP
  uint16_t* src_b = Wm;        // overlay: consumed by K/V-GEMMs before attn writes Wm
  const size_t needBase = (1ull << 20) + 5ull * 16777216ull;
  const size_t needFull = needBase + 8ull * 1048576ull * 2ull / 2ull;  // + 8MB bf16 weights
  uint16_t* Wb = (uint16_t*)(ws + needBase);
  const int useConvW = (ws_size >= needFull) ? 1 : 0;
  if (ws_size < needBase) {  // diagnostic fallback: distinctive pattern
    fill_pattern<<<1024, 256, 0, stream>>>((uint32_t*)d_out, (size_t)out_size / 2);
    return;
  }

  detect_kernel<<<1, 256, 0, stream>>>(d_in[3], d_in[2], d_in[4], d_in[6], d_in[8], d_in[10], hdr, bias);

  convert_kernel<<<4096, 256, 0, stream>>>(d_in[0], d_in[1], d_in[3], d_in[5], d_in[7], d_in[9],
                                           dec_b, src_b, Wb, hdr, useConvW);

  const void* Wq = useConvW ? (const void*)(Wb + 0 * 1048576) : (const void*)d_in[3];
  const void* Wk = useConvW ? (const void*)(Wb + 1 * 1048576) : (const void*)d_in[5];
  const void* Wv = useConvW ? (const void*)(Wb + 2 * 1048576) : (const void*)d_in[7];
  const void* Wo = useConvW ? (const void*)(Wb + 3 * 1048576) : (const void*)d_in[9];

  dim3 gg(64, 8);
  gemm_bt<MQ><<<gg, 256, 0, stream>>>(dec_b, Wq, bias, hdr, Q, 0.125f, useConvW);
  gemm_bt<MK><<<gg, 256, 0, stream>>>(src_b, Wk, bias + 1024, hdr, K, 1.f, useConvW);
  gemm_bt<MV><<<gg, 256, 0, stream>>>(src_b, Wv, bias + 2048, hdr, V, 1.f, useConvW);

  attn_kernel<<<512, 256, 0, stream>>>(Q, K, V, hdr, AP, Wm);

  wtrans_kernel<<<dim3(16, 32), 256, 0, stream>>>(Wm, hdr, d_out);

  gemm_bt<MO><<<gg, 256, 0, stream>>>(AP, Wo, bias + 3072, hdr, d_out, 1.f, useConvW);
}